// Round 1
// baseline (824.144 us; speedup 1.0000x reference)
//
#include <hip/hip_runtime.h>
#include <stdint.h>

// Problem constants (B=4, N=2048, F=256, H=4, C=64)
#define NNODE 2048
#define NHEAD 4
#define CDIM  64
#define NBATCH 4

// ---------------------------------------------------------------------------
// Pack adj (int32 0/1, [B][N][N]) into bitmask words: adjp[(b*N+n)*32 + m/64],
// bit i of word w = adj[b][n][w*64+i] != 0.
// ---------------------------------------------------------------------------
__global__ __launch_bounds__(256) void pack_adj(const int* __restrict__ adj,
                                                unsigned long long* __restrict__ adjp) {
    int gid = blockIdx.x * 256 + threadIdx.x;
    unsigned long long m = __ballot(adj[gid] != 0);
    if ((threadIdx.x & 63) == 0) adjp[gid >> 6] = m;
}

// ---------------------------------------------------------------------------
// QKV GEMM: X [8192][256] fp32  @  W (256x256 each of Wq,Wk,Wv)
// Output layout: Q/K/V as [B*H][N][C]  ( (b*4+h)*2048*64 + n*64 + c )
// Tile: 64x64, 256 threads, 4x4 micro-tile, K-step 64.
// ---------------------------------------------------------------------------
__global__ __launch_bounds__(256) void qkv_gemm(
    const float* __restrict__ X,
    const float* __restrict__ Wq, const float* __restrict__ Wk, const float* __restrict__ Wv,
    float* __restrict__ Q, float* __restrict__ K, float* __restrict__ V)
{
    __shared__ float As[64][68];   // As[k][m]  (transposed A tile), stride 68 -> 272B (16B-aligned)
    __shared__ float Bs[64][68];   // Bs[k][n]

    const int tid = threadIdx.x;
    const int tx = tid & 15, ty = tid >> 4;
    const int row0 = blockIdx.x * 64;        // 0..8191 in steps of 64
    const int nblk = blockIdx.y;             // 0..11
    const int which = nblk >> 2;             // 0=q,1=k,2=v
    const int h = nblk & 3;
    const float* __restrict__ W  = (which == 0) ? Wq : (which == 1) ? Wk : Wv;
    float* __restrict__ dst      = (which == 0) ? Q  : (which == 1) ? K  : V;

    const int sr = tid >> 2;            // 0..63
    const int sc = (tid & 3) * 16;      // 0,16,32,48

    float acc[4][4] = {};

    for (int k0 = 0; k0 < 256; k0 += 64) {
        __syncthreads();
        #pragma unroll
        for (int t = 0; t < 4; ++t) {
            float4 a = *reinterpret_cast<const float4*>(&X[(size_t)(row0 + sr) * 256 + k0 + sc + t * 4]);
            As[sc + t * 4 + 0][sr] = a.x;
            As[sc + t * 4 + 1][sr] = a.y;
            As[sc + t * 4 + 2][sr] = a.z;
            As[sc + t * 4 + 3][sr] = a.w;
            float4 b = *reinterpret_cast<const float4*>(&W[(size_t)(k0 + sr) * 256 + h * 64 + sc + t * 4]);
            *reinterpret_cast<float4*>(&Bs[sr][sc + t * 4]) = b;
        }
        __syncthreads();
        #pragma unroll 8
        for (int kk = 0; kk < 64; ++kk) {
            float4 a4 = *reinterpret_cast<const float4*>(&As[kk][ty * 4]);
            float4 b4 = *reinterpret_cast<const float4*>(&Bs[kk][tx * 4]);
            const float av[4] = {a4.x, a4.y, a4.z, a4.w};
            const float bv[4] = {b4.x, b4.y, b4.z, b4.w};
            #pragma unroll
            for (int i = 0; i < 4; ++i) {
                #pragma unroll
                for (int j = 0; j < 4; ++j) acc[i][j] = fmaf(av[i], bv[j], acc[i][j]);
            }
        }
    }

    #pragma unroll
    for (int i = 0; i < 4; ++i) {
        int row = row0 + ty * 4 + i;
        int b = row >> 11, n = row & 2047;
        float4 o = make_float4(acc[i][0], acc[i][1], acc[i][2], acc[i][3]);
        *reinterpret_cast<float4*>(&dst[((size_t)(b * 4 + h) * 2048 + n) * 64 + tx * 4]) = o;
    }
}

// ---------------------------------------------------------------------------
// Fused masked-softmax attention (flash style), fp32.
// Grid: (qt=32, h=4, b=4), 256 threads. Per block: 64 q-rows of one (b,h).
// Exactly emulates: a = where(adj>0, qk/8, -1e30); a -= rowmax;
//                   e = exp(a)*adj; p = e/(sum e + 1e-16); out = p@v + bias (+relu)
// ---------------------------------------------------------------------------
__global__ __launch_bounds__(256) void gat_attn(
    const float* __restrict__ Q, const float* __restrict__ K, const float* __restrict__ V,
    const unsigned long long* __restrict__ adjp,
    const float* __restrict__ bias, float* __restrict__ out, const int relu)
{
    __shared__ float Qs[64][68];             // Qs[r][f]
    __shared__ float Ks[64][68];             // score phase: Ks[f][m]; then reused as Ps[r][m]
    __shared__ float Vs[64][68];             // Vs[m][c]
    __shared__ unsigned long long Mb[64];    // mask word per q-row for current m-tile

    const int tid = threadIdx.x;
    const int tx = tid & 15, ty = tid >> 4;
    const int qt = blockIdx.x;
    const int h  = blockIdx.y;
    const int b  = blockIdx.z;
    const int bh = b * 4 + h;
    const float* __restrict__ Qp = Q + (size_t)bh * NNODE * CDIM;
    const float* __restrict__ Kp = K + (size_t)bh * NNODE * CDIM;
    const float* __restrict__ Vp = V + (size_t)bh * NNODE * CDIM;

    const int sr = tid >> 2;            // 0..63
    const int sc = (tid & 3) * 16;      // 0,16,32,48

    // stage Q tile (fenced by the first in-loop barrier)
    #pragma unroll
    for (int t = 0; t < 4; ++t) {
        float4 qv = *reinterpret_cast<const float4*>(&Qp[(size_t)(qt * 64 + sr) * 64 + sc + t * 4]);
        *reinterpret_cast<float4*>(&Qs[sr][sc + t * 4]) = qv;
    }

    float acc[4][4] = {};
    float mrow[4], lrow[4];
    #pragma unroll
    for (int i = 0; i < 4; ++i) { mrow[i] = -1e30f; lrow[i] = 0.f; }

    for (int mt = 0; mt < NNODE; mt += 64) {
        __syncthreads();   // previous PV done with Vs/Ps (also fences Qs staging on iter 0)
        #pragma unroll
        for (int t = 0; t < 4; ++t) {
            float4 kv = *reinterpret_cast<const float4*>(&Kp[(size_t)(mt + sr) * 64 + sc + t * 4]);
            Ks[sc + t * 4 + 0][sr] = kv.x;
            Ks[sc + t * 4 + 1][sr] = kv.y;
            Ks[sc + t * 4 + 2][sr] = kv.z;
            Ks[sc + t * 4 + 3][sr] = kv.w;
            float4 vv = *reinterpret_cast<const float4*>(&Vp[(size_t)(mt + sr) * 64 + sc + t * 4]);
            *reinterpret_cast<float4*>(&Vs[sr][sc + t * 4]) = vv;
        }
        if (tid < 64) Mb[tid] = adjp[(size_t)(b * NNODE + qt * 64 + tid) * 32 + (mt >> 6)];
        __syncthreads();

        // ---- scores: s[i][j] = dot64(Q row 4ty+i, K col 4tx+j) ----
        float s[4][4] = {};
        #pragma unroll 4
        for (int f = 0; f < 64; f += 4) {
            float4 qv[4], kv[4];
            #pragma unroll
            for (int i = 0; i < 4; ++i) qv[i] = *reinterpret_cast<const float4*>(&Qs[ty * 4 + i][f]);
            #pragma unroll
            for (int t = 0; t < 4; ++t) kv[t] = *reinterpret_cast<const float4*>(&Ks[f + t][tx * 4]);
            #pragma unroll
            for (int t = 0; t < 4; ++t) {
                #pragma unroll
                for (int i = 0; i < 4; ++i) {
                    const float qe = (t == 0) ? qv[i].x : (t == 1) ? qv[i].y : (t == 2) ? qv[i].z : qv[i].w;
                    s[i][0] = fmaf(qe, kv[t].x, s[i][0]);
                    s[i][1] = fmaf(qe, kv[t].y, s[i][1]);
                    s[i][2] = fmaf(qe, kv[t].z, s[i][2]);
                    s[i][3] = fmaf(qe, kv[t].w, s[i][3]);
                }
            }
        }

        // ---- mask + online softmax ----
        float p[4][4], tm[4];
        #pragma unroll
        for (int i = 0; i < 4; ++i) {
            unsigned long long mb = Mb[ty * 4 + i];
            float rowmax = -1e30f;
            #pragma unroll
            for (int j = 0; j < 4; ++j) {
                float a = s[i][j] * 0.125f;                 // 1/sqrt(64)
                bool on = (mb >> (unsigned)(tx * 4 + j)) & 1ULL;
                a = on ? a : -1e30f;
                p[i][j] = a;
                rowmax = fmaxf(rowmax, a);
            }
            tm[i] = rowmax;
        }
        #pragma unroll
        for (int d = 1; d < 16; d <<= 1) {
            #pragma unroll
            for (int i = 0; i < 4; ++i) tm[i] = fmaxf(tm[i], __shfl_xor(tm[i], d));
        }
        float sf[4];
        #pragma unroll
        for (int i = 0; i < 4; ++i) {
            float mnew = fmaxf(mrow[i], tm[i]);
            sf[i] = expf(mrow[i] - mnew);   // exactly 1 when both -1e30; 0 when mrow=-1e30,mnew finite
            mrow[i] = mnew;
        }
        float rs[4];
        #pragma unroll
        for (int i = 0; i < 4; ++i) {
            float r = 0.f;
            #pragma unroll
            for (int j = 0; j < 4; ++j) {
                float e = (p[i][j] <= -9e29f) ? 0.f : expf(p[i][j] - mrow[i]);
                p[i][j] = e;
                r += e;
            }
            rs[i] = r;
        }
        #pragma unroll
        for (int d = 1; d < 16; d <<= 1) {
            #pragma unroll
            for (int i = 0; i < 4; ++i) rs[i] += __shfl_xor(rs[i], d);
        }
        #pragma unroll
        for (int i = 0; i < 4; ++i) {
            lrow[i] = lrow[i] * sf[i] + rs[i];
            #pragma unroll
            for (int j = 0; j < 4; ++j) acc[i][j] *= sf[i];
        }

        __syncthreads();   // everyone done reading Ks (scores)
        #pragma unroll
        for (int i = 0; i < 4; ++i) {
            float4 pv = make_float4(p[i][0], p[i][1], p[i][2], p[i][3]);
            *reinterpret_cast<float4*>(&Ks[ty * 4 + i][tx * 4]) = pv;   // Ps[r][m]
        }
        __syncthreads();

        // ---- PV: acc[i][j] += sum_m Ps[4ty+i][m] * Vs[m][4tx+j] ----
        #pragma unroll 4
        for (int m = 0; m < 64; m += 4) {
            float4 pr[4], vr[4];
            #pragma unroll
            for (int i = 0; i < 4; ++i) pr[i] = *reinterpret_cast<const float4*>(&Ks[ty * 4 + i][m]);
            #pragma unroll
            for (int t = 0; t < 4; ++t) vr[t] = *reinterpret_cast<const float4*>(&Vs[m + t][tx * 4]);
            #pragma unroll
            for (int t = 0; t < 4; ++t) {
                #pragma unroll
                for (int i = 0; i < 4; ++i) {
                    const float pe = (t == 0) ? pr[i].x : (t == 1) ? pr[i].y : (t == 2) ? pr[i].z : pr[i].w;
                    acc[i][0] = fmaf(pe, vr[t].x, acc[i][0]);
                    acc[i][1] = fmaf(pe, vr[t].y, acc[i][1]);
                    acc[i][2] = fmaf(pe, vr[t].z, acc[i][2]);
                    acc[i][3] = fmaf(pe, vr[t].w, acc[i][3]);
                }
            }
        }
    }

    // ---- epilogue: divide, bias, (relu), store ----
    const float4 bv = *reinterpret_cast<const float4*>(&bias[h * 64 + tx * 4]);
    #pragma unroll
    for (int i = 0; i < 4; ++i) {
        float inv = 1.f / (lrow[i] + 1e-16f);
        float4 o;
        o.x = acc[i][0] * inv + bv.x;
        o.y = acc[i][1] * inv + bv.y;
        o.z = acc[i][2] * inv + bv.z;
        o.w = acc[i][3] * inv + bv.w;
        if (relu) {
            o.x = fmaxf(o.x, 0.f); o.y = fmaxf(o.y, 0.f);
            o.z = fmaxf(o.z, 0.f); o.w = fmaxf(o.w, 0.f);
        }
        int n = qt * 64 + ty * 4 + i;
        *reinterpret_cast<float4*>(&out[((size_t)(b * NNODE + n)) * 256 + h * 64 + tx * 4]) = o;
    }
}

// ---------------------------------------------------------------------------
extern "C" void kernel_launch(void* const* d_in, const int* in_sizes, int n_in,
                              void* d_out, int out_size, void* d_ws, size_t ws_size,
                              hipStream_t stream) {
    const float* x   = (const float*)d_in[0];
    const int*   adj = (const int*)d_in[1];
    const float* Wq1 = (const float*)d_in[2];
    const float* Wk1 = (const float*)d_in[3];
    const float* Wv1 = (const float*)d_in[4];
    const float* b1  = (const float*)d_in[5];
    const float* Wq2 = (const float*)d_in[6];
    const float* Wk2 = (const float*)d_in[7];
    const float* Wv2 = (const float*)d_in[8];
    const float* b2  = (const float*)d_in[9];
    float* outp = (float*)d_out;

    // workspace layout (floats): q,k,v,h = 2M each (8MB), then adjp (2MB)
    float* q    = (float*)d_ws;
    float* k    = q + 2097152;
    float* v    = k + 2097152;
    float* hbuf = v + 2097152;
    unsigned long long* adjp = (unsigned long long*)(hbuf + 2097152);

    pack_adj<<<65536, 256, 0, stream>>>(adj, adjp);

    qkv_gemm<<<dim3(128, 12), 256, 0, stream>>>(x, Wq1, Wk1, Wv1, q, k, v);
    gat_attn<<<dim3(32, 4, 4), 256, 0, stream>>>(q, k, v, adjp, b1, hbuf, 1);

    qkv_gemm<<<dim3(128, 12), 256, 0, stream>>>(hbuf, Wq2, Wk2, Wv2, q, k, v);
    gat_attn<<<dim3(32, 4, 4), 256, 0, stream>>>(q, k, v, adjp, b2, outp, 0);
}

// Round 4
// 479.164 us; speedup vs baseline: 1.7200x; 1.7200x over previous
//
#include <hip/hip_runtime.h>
#include <hip/hip_fp16.h>
#include <stdint.h>

// Problem constants (B=4, N=2048, F=256, H=4, C=64)
#define NNODE 2048

typedef _Float16 half8 __attribute__((ext_vector_type(8)));
typedef __fp16   fp16x2 __attribute__((ext_vector_type(2)));
typedef float    f32x16 __attribute__((ext_vector_type(16)));

__device__ __forceinline__ f32x16 zero16() {
    f32x16 z;
    #pragma unroll
    for (int i = 0; i < 16; ++i) z[i] = 0.f;
    return z;
}

// ---------------------------------------------------------------------------
// Pack adj (int32 0/1, [B][N][N]) into bitmask words.
// ---------------------------------------------------------------------------
__global__ __launch_bounds__(256) void pack_adj(const int* __restrict__ adj,
                                                unsigned long long* __restrict__ adjp) {
    int gid = blockIdx.x * 256 + threadIdx.x;
    unsigned long long m = __ballot(adj[gid] != 0);
    if ((threadIdx.x & 63) == 0) adjp[gid >> 6] = m;
}

// ---------------------------------------------------------------------------
// QKV GEMM (fp32 VALU). Epilogue: Q -> (qhi,qlo) fp16 split scaled by 0.125,
// K -> (khi,klo) fp16 split, V -> fp32 (transposed+split by next kernel).
// Layout of all q/k outputs: [bh][n][64].
// ---------------------------------------------------------------------------
__global__ __launch_bounds__(256) void qkv_gemm(
    const float* __restrict__ X,
    const float* __restrict__ Wq, const float* __restrict__ Wk, const float* __restrict__ Wv,
    __half* __restrict__ Qhi, __half* __restrict__ Qlo,
    __half* __restrict__ Khi, __half* __restrict__ Klo,
    float* __restrict__ V)
{
    __shared__ float As[64][68];
    __shared__ float Bs[64][68];

    const int tid = threadIdx.x;
    const int tx = tid & 15, ty = tid >> 4;
    const int row0 = blockIdx.x * 64;
    const int nblk = blockIdx.y;
    const int which = nblk >> 2;             // 0=q,1=k,2=v
    const int h = nblk & 3;
    const float* __restrict__ W = (which == 0) ? Wq : (which == 1) ? Wk : Wv;

    const int sr = tid >> 2;
    const int sc = (tid & 3) * 16;

    float acc[4][4] = {};

    for (int k0 = 0; k0 < 256; k0 += 64) {
        __syncthreads();
        #pragma unroll
        for (int t = 0; t < 4; ++t) {
            float4 a = *reinterpret_cast<const float4*>(&X[(size_t)(row0 + sr) * 256 + k0 + sc + t * 4]);
            As[sc + t * 4 + 0][sr] = a.x;
            As[sc + t * 4 + 1][sr] = a.y;
            As[sc + t * 4 + 2][sr] = a.z;
            As[sc + t * 4 + 3][sr] = a.w;
            float4 b = *reinterpret_cast<const float4*>(&W[(size_t)(k0 + sr) * 256 + h * 64 + sc + t * 4]);
            *reinterpret_cast<float4*>(&Bs[sr][sc + t * 4]) = b;
        }
        __syncthreads();
        #pragma unroll 8
        for (int kk = 0; kk < 64; ++kk) {
            float4 a4 = *reinterpret_cast<const float4*>(&As[kk][ty * 4]);
            float4 b4 = *reinterpret_cast<const float4*>(&Bs[kk][tx * 4]);
            const float av[4] = {a4.x, a4.y, a4.z, a4.w};
            const float bv[4] = {b4.x, b4.y, b4.z, b4.w};
            #pragma unroll
            for (int i = 0; i < 4; ++i)
                #pragma unroll
                for (int j = 0; j < 4; ++j) acc[i][j] = fmaf(av[i], bv[j], acc[i][j]);
        }
    }

    if (which == 2) {
        #pragma unroll
        for (int i = 0; i < 4; ++i) {
            int row = row0 + ty * 4 + i;
            int b = row >> 11, n = row & 2047;
            float4 o = make_float4(acc[i][0], acc[i][1], acc[i][2], acc[i][3]);
            *reinterpret_cast<float4*>(&V[((size_t)(b * 4 + h) * 2048 + n) * 64 + tx * 4]) = o;
        }
    } else {
        const float qs = (which == 0) ? 0.125f : 1.0f;   // fold 1/sqrt(64) into Q
        __half* __restrict__ Dh = (which == 0) ? Qhi : Khi;
        __half* __restrict__ Dl = (which == 0) ? Qlo : Klo;
        #pragma unroll
        for (int i = 0; i < 4; ++i) {
            int row = row0 + ty * 4 + i;
            int b = row >> 11, n = row & 2047;
            size_t idx = ((size_t)(b * 4 + h) * 2048 + n) * 64 + tx * 4;
            union { __half h[4]; uint2 u; } ph, pl;
            #pragma unroll
            for (int j = 0; j < 4; ++j) {
                float v = acc[i][j] * qs;
                __half hv = __float2half(v);
                ph.h[j] = hv;
                pl.h[j] = __float2half(v - __half2float(hv));
            }
            *reinterpret_cast<uint2*>(&Dh[idx]) = ph.u;
            *reinterpret_cast<uint2*>(&Dl[idx]) = pl.u;
        }
    }
}

// ---------------------------------------------------------------------------
// V [bh][2048][64] fp32 -> vthi/vtlo [bh][64][2048] fp16 split (transposed).
// ---------------------------------------------------------------------------
__global__ __launch_bounds__(256) void transpose_split_v(
    const float* __restrict__ V, __half* __restrict__ vthi, __half* __restrict__ vtlo)
{
    __shared__ float T[64][65];
    const int bh = blockIdx.y;
    const int m0 = blockIdx.x * 64;
    const float* __restrict__ Vb = V + (size_t)bh * 2048 * 64;
    const int t = threadIdx.x;
    #pragma unroll
    for (int p = 0; p < 4; ++p) {
        int id = p * 256 + t;         // 0..1023
        int m = id >> 4;
        int c4 = (id & 15) * 4;
        float4 v4 = *reinterpret_cast<const float4*>(Vb + (size_t)(m0 + m) * 64 + c4);
        T[m][c4 + 0] = v4.x; T[m][c4 + 1] = v4.y; T[m][c4 + 2] = v4.z; T[m][c4 + 3] = v4.w;
    }
    __syncthreads();
    const int c = t >> 2, mc = (t & 3) * 16;
    union { __half h[16]; uint4 u[2]; } hs, ls;
    #pragma unroll
    for (int i = 0; i < 16; ++i) {
        float v = T[mc + i][c];
        __half hv = __float2half(v);
        hs.h[i] = hv;
        ls.h[i] = __float2half(v - __half2float(hv));
    }
    size_t dst = (size_t)(bh * 64 + c) * 2048 + m0 + mc;
    *reinterpret_cast<uint4*>(&vthi[dst])     = hs.u[0];
    *reinterpret_cast<uint4*>(&vthi[dst + 8]) = hs.u[1];
    *reinterpret_cast<uint4*>(&vtlo[dst])     = ls.u[0];
    *reinterpret_cast<uint4*>(&vtlo[dst + 8]) = ls.u[1];
}

// ---------------------------------------------------------------------------
// Fused masked flash attention on MFMA (split fp16, swapped QK^T).
// Grid: 1024 blocks x 256 threads. Block = (bh, 32 q-rows); wave w handles
// m-chunk [w*512, w*512+512). In-LDS merge of the 4 partials at the end.
// ---------------------------------------------------------------------------
__global__ __launch_bounds__(256) void gat_attn(
    const __half* __restrict__ qhi, const __half* __restrict__ qlo,
    const __half* __restrict__ khi, const __half* __restrict__ klo,
    const __half* __restrict__ vthi, const __half* __restrict__ vtlo,
    const unsigned long long* __restrict__ adjp,
    const float* __restrict__ bias, float* __restrict__ out, const int relu)
{
    // XCD-chunked swizzle: 128 consecutive logical blocks per XCD (1024 = 8*128)
    const int lid = (blockIdx.x & 7) * 128 + (blockIdx.x >> 3);
    const int bh = lid >> 6, qt = lid & 63;
    const int b = bh >> 2, h = bh & 3;
    const int tid = threadIdx.x;
    const int wave = tid >> 6;
    const int lane = tid & 63;
    const int lq = lane & 31;          // q-col within tile
    const int hh = lane >> 5;          // lane half
    const int q0 = qt * 32;

    const size_t qkbase = (size_t)bh * 2048 * 64;
    const __half* __restrict__ khb = khi + qkbase;
    const __half* __restrict__ klb = klo + qkbase;
    const __half* __restrict__ vhb = vthi + (size_t)bh * 64 * 2048;
    const __half* __restrict__ vlb = vtlo + (size_t)bh * 64 * 2048;

    // Q fragments (B-operand: col = lane&31 = q, k = 8*hh + e), 4 k-steps
    half8 qfh[4], qfl[4];
    {
        const __half* qr_h = qhi + qkbase + (size_t)(q0 + lq) * 64 + 8 * hh;
        const __half* qr_l = qlo + qkbase + (size_t)(q0 + lq) * 64 + 8 * hh;
        #pragma unroll
        for (int ks = 0; ks < 4; ++ks) {
            qfh[ks] = *reinterpret_cast<const half8*>(qr_h + ks * 16);
            qfl[ks] = *reinterpret_cast<const half8*>(qr_l + ks * 16);
        }
    }

    f32x16 o0 = zero16(), o1 = zero16();
    float mrun = -1e30f, lrun = 0.f;

    const unsigned long long* __restrict__ wrow = adjp + (size_t)(b * 2048 + q0 + lq) * 32;
    const int mbase = wave * 512;

    #pragma unroll 1
    for (int mw = 0; mw < 512; mw += 64) {
        const int mglob = mbase + mw;
        const unsigned long long wmask = wrow[mglob >> 6];

        #pragma unroll
        for (int hi2 = 0; hi2 < 2; ++hi2) {
            const int mt = mglob + hi2 * 32;

            // ---- scores S^T = K * Q^T (3-way split) ----
            const __half* krh = khb + (size_t)(mt + lq) * 64 + 8 * hh;
            const __half* krl = klb + (size_t)(mt + lq) * 64 + 8 * hh;
            f32x16 st = zero16();
            #pragma unroll
            for (int ks = 0; ks < 4; ++ks) {
                half8 kh = *reinterpret_cast<const half8*>(krh + ks * 16);
                half8 kl = *reinterpret_cast<const half8*>(krl + ks * 16);
                st = __builtin_amdgcn_mfma_f32_32x32x16_f16(kh, qfh[ks], st, 0, 0, 0);
                st = __builtin_amdgcn_mfma_f32_32x32x16_f16(kl, qfh[ks], st, 0, 0, 0);
                st = __builtin_amdgcn_mfma_f32_32x32x16_f16(kh, qfl[ks], st, 0, 0, 0);
            }

            // ---- mask + online softmax (in-lane over 16 regs + 1 cross-half) ----
            const unsigned long long wsh = wmask >> ((hi2 << 5) + 4 * hh);
            float tv[16];
            unsigned int bits = 0;
            float pm = -1e30f;
            #pragma unroll
            for (int i = 0; i < 16; ++i) {
                const int sh = (i & 3) + 8 * (i >> 2);
                unsigned int on = (unsigned int)((wsh >> sh) & 1ULL);
                float tvv = on ? st[i] : -1e30f;
                tv[i] = tvv;
                bits |= on << i;
                pm = fmaxf(pm, tvv);
            }
            pm = fmaxf(pm, __shfl_xor(pm, 32, 64));
            const float mnew = fmaxf(mrun, pm);
            const float sf = __expf(mrun - mnew);   // 1 when both -1e30; 0 when new max appears
            float e[16];
            float ps = 0.f;
            #pragma unroll
            for (int i = 0; i < 16; ++i) {
                float ev = ((bits >> i) & 1u) ? __expf(tv[i] - mnew) : 0.f;
                e[i] = ev;
                ps += ev;
            }
            ps += __shfl_xor(ps, 32, 64);
            lrun = lrun * sf + ps;
            mrun = mnew;
            o0 *= sf;
            o1 *= sf;

            // ---- P -> split fp16 B-frags (cvt_pkrtz + cross-half exchange) + PV ----
            #pragma unroll
            for (int t2 = 0; t2 < 2; ++t2) {
                unsigned int Hp[4], Lp[4];
                #pragma unroll
                for (int p2 = 0; p2 < 4; ++p2) {
                    float ea = e[8 * t2 + 2 * p2], eb = e[8 * t2 + 2 * p2 + 1];
                    union { fp16x2 f; unsigned int u; } ch, cl;
                    ch.f = __builtin_amdgcn_cvt_pkrtz(ea, eb);
                    float fa = (float)ch.f[0], fb = (float)ch.f[1];
                    cl.f = __builtin_amdgcn_cvt_pkrtz(ea - fa, eb - fb);
                    Hp[p2] = ch.u; Lp[p2] = cl.u;
                }
                unsigned int Hx0 = (unsigned)__shfl_xor((int)Hp[0], 32, 64);
                unsigned int Hx1 = (unsigned)__shfl_xor((int)Hp[1], 32, 64);
                unsigned int Hx2 = (unsigned)__shfl_xor((int)Hp[2], 32, 64);
                unsigned int Hx3 = (unsigned)__shfl_xor((int)Hp[3], 32, 64);
                unsigned int Lx0 = (unsigned)__shfl_xor((int)Lp[0], 32, 64);
                unsigned int Lx1 = (unsigned)__shfl_xor((int)Lp[1], 32, 64);
                unsigned int Lx2 = (unsigned)__shfl_xor((int)Lp[2], 32, 64);
                unsigned int Lx3 = (unsigned)__shfl_xor((int)Lp[3], 32, 64);
                union { unsigned int u[4]; half8 hv; } Bh, Bl;
                Bh.u[0] = hh ? Hx2 : Hp[0]; Bh.u[1] = hh ? Hx3 : Hp[1];
                Bh.u[2] = hh ? Hp[2] : Hx0; Bh.u[3] = hh ? Hp[3] : Hx1;
                Bl.u[0] = hh ? Lx2 : Lp[0]; Bl.u[1] = hh ? Lx3 : Lp[1];
                Bl.u[2] = hh ? Lp[2] : Lx0; Bl.u[3] = hh ? Lp[3] : Lx1;

                const __half* v0h = vhb + (size_t)lq * 2048 + mt + 16 * t2 + 8 * hh;
                const __half* v0l = vlb + (size_t)lq * 2048 + mt + 16 * t2 + 8 * hh;
                half8 va = *reinterpret_cast<const half8*>(v0h);
                half8 vb = *reinterpret_cast<const half8*>(v0h + 32 * 2048);
                half8 wa = *reinterpret_cast<const half8*>(v0l);
                half8 wb = *reinterpret_cast<const half8*>(v0l + 32 * 2048);

                o0 = __builtin_amdgcn_mfma_f32_32x32x16_f16(va, Bh.hv, o0, 0, 0, 0);
                o0 = __builtin_amdgcn_mfma_f32_32x32x16_f16(wa, Bh.hv, o0, 0, 0, 0);
                o0 = __builtin_amdgcn_mfma_f32_32x32x16_f16(va, Bl.hv, o0, 0, 0, 0);
                o1 = __builtin_amdgcn_mfma_f32_32x32x16_f16(vb, Bh.hv, o1, 0, 0, 0);
                o1 = __builtin_amdgcn_mfma_f32_32x32x16_f16(wb, Bh.hv, o1, 0, 0, 0);
                o1 = __builtin_amdgcn_mfma_f32_32x32x16_f16(vb, Bl.hv, o1, 0, 0, 0);
            }
        }
    }

    // ---- in-LDS merge of the 4 m-chunk partials ----
    __shared__ float OS[4][64][33];
    __shared__ float MS[4][32];
    __shared__ float LS[4][32];

    #pragma unroll
    for (int ct = 0; ct < 2; ++ct) {
        #pragma unroll
        for (int i = 0; i < 16; ++i) {
            int c = 32 * ct + (i & 3) + 8 * (i >> 2) + 4 * hh;
            OS[wave][c][lq] = ct ? o1[i] : o0[i];
        }
    }
    if (hh == 0) { MS[wave][lq] = mrun; LS[wave][lq] = lrun; }
    __syncthreads();

    const int q = tid >> 3, c8 = (tid & 7) * 8;
    float m0v = MS[0][q], m1v = MS[1][q], m2v = MS[2][q], m3v = MS[3][q];
    float M = fmaxf(fmaxf(m0v, m1v), fmaxf(m2v, m3v));
    float w0 = __expf(m0v - M), w1 = __expf(m1v - M), w2 = __expf(m2v - M), w3 = __expf(m3v - M);
    float L = LS[0][q] * w0 + LS[1][q] * w1 + LS[2][q] * w2 + LS[3][q] * w3;
    float inv = 1.f / (L + 1e-16f);
    float res[8];
    #pragma unroll
    for (int j = 0; j < 8; ++j) {
        int c = c8 + j;
        float o = OS[0][c][q] * w0 + OS[1][c][q] * w1 + OS[2][c][q] * w2 + OS[3][c][q] * w3;
        float val = o * inv + bias[h * 64 + c];
        if (relu) val = fmaxf(val, 0.f);
        res[j] = val;
    }
    float* op = out + ((size_t)(b * 2048) + q0 + q) * 256 + h * 64 + c8;
    *reinterpret_cast<float4*>(op)     = make_float4(res[0], res[1], res[2], res[3]);
    *reinterpret_cast<float4*>(op + 4) = make_float4(res[4], res[5], res[6], res[7]);
}

// ---------------------------------------------------------------------------
extern "C" void kernel_launch(void* const* d_in, const int* in_sizes, int n_in,
                              void* d_out, int out_size, void* d_ws, size_t ws_size,
                              hipStream_t stream) {
    const float* x   = (const float*)d_in[0];
    const int*   adj = (const int*)d_in[1];
    const float* Wq1 = (const float*)d_in[2];
    const float* Wk1 = (const float*)d_in[3];
    const float* Wv1 = (const float*)d_in[4];
    const float* b1  = (const float*)d_in[5];
    const float* Wq2 = (const float*)d_in[6];
    const float* Wk2 = (const float*)d_in[7];
    const float* Wv2 = (const float*)d_in[8];
    const float* b2  = (const float*)d_in[9];
    float* outp = (float*)d_out;

    // workspace layout (bytes):
    char* ws = (char*)d_ws;
    unsigned long long* adjp = (unsigned long long*)ws;        //  2 MB
    __half* qhi = (__half*)(ws + (2u << 20));                  //  4 MB each
    __half* qlo = (__half*)(ws + (6u << 20));
    __half* khi = (__half*)(ws + (10u << 20));
    __half* klo = (__half*)(ws + (14u << 20));
    float*  v   = (float*) (ws + (18u << 20));                 //  8 MB
    __half* vthi= (__half*)(ws + (26u << 20));                 //  4 MB each
    __half* vtlo= (__half*)(ws + (30u << 20));
    float*  hbuf= (float*) (ws + (34u << 20));                 //  8 MB  (total 42 MB)

    pack_adj<<<65536, 256, 0, stream>>>(adj, adjp);

    qkv_gemm<<<dim3(128, 12), 256, 0, stream>>>(x, Wq1, Wk1, Wv1, qhi, qlo, khi, klo, v);
    transpose_split_v<<<dim3(32, 16), 256, 0, stream>>>(v, vthi, vtlo);
    gat_attn<<<1024, 256, 0, stream>>>(qhi, qlo, khi, klo, vthi, vtlo, adjp, b1, hbuf, 1);

    qkv_gemm<<<dim3(128, 12), 256, 0, stream>>>(hbuf, Wq2, Wk2, Wv2, qhi, qlo, khi, klo, v);
    transpose_split_v<<<dim3(32, 16), 256, 0, stream>>>(v, vthi, vtlo);
    gat_attn<<<1024, 256, 0, stream>>>(qhi, qlo, khi, klo, vthi, vtlo, adjp, b2, outp, 0);
}

// Round 7
// 379.522 us; speedup vs baseline: 2.1715x; 1.2625x over previous
//
#include <hip/hip_runtime.h>
#include <hip/hip_fp16.h>
#include <stdint.h>

// Problem constants (B=4, N=2048, F=256, H=4, C=64)
#define NNODE 2048

typedef _Float16 half8 __attribute__((ext_vector_type(8)));
typedef __fp16   fp16x2 __attribute__((ext_vector_type(2)));
typedef float    f32x16 __attribute__((ext_vector_type(16)));

__device__ __forceinline__ f32x16 zero16() {
    f32x16 z;
    #pragma unroll
    for (int i = 0; i < 16; ++i) z[i] = 0.f;
    return z;
}

// ---------------------------------------------------------------------------
// Pack adj (int32 0/1, [B][N][N]) into bitmask words.
// ---------------------------------------------------------------------------
__global__ __launch_bounds__(256) void pack_adj(const int* __restrict__ adj,
                                                unsigned long long* __restrict__ adjp) {
    int gid = blockIdx.x * 256 + threadIdx.x;
    unsigned long long m = __ballot(adj[gid] != 0);
    if ((threadIdx.x & 63) == 0) adjp[gid >> 6] = m;
}

// ---------------------------------------------------------------------------
// x fp32 [8192][256] -> xhi/xlo fp16 split. 4 floats/thread.
// ---------------------------------------------------------------------------
__global__ __launch_bounds__(256) void split_x(const float* __restrict__ x,
                                               __half* __restrict__ xhi,
                                               __half* __restrict__ xlo) {
    size_t gid = (size_t)blockIdx.x * 256 + threadIdx.x;
    float4 v = *reinterpret_cast<const float4*>(x + gid * 4);
    float vv[4] = {v.x, v.y, v.z, v.w};
    union { __half h[4]; uint2 u; } ph, pl;
    #pragma unroll
    for (int j = 0; j < 4; ++j) {
        __half hv = __float2half(vv[j]);
        ph.h[j] = hv;
        pl.h[j] = __float2half(vv[j] - __half2float(hv));
    }
    *reinterpret_cast<uint2*>(xhi + gid * 4) = ph.u;
    *reinterpret_cast<uint2*>(xlo + gid * 4) = pl.u;
}

// ---------------------------------------------------------------------------
// 6 weight matrices [256][256] fp32 -> wth/wtl [6][n][k] fp16 split TRANSPOSED
// (wt[which][n][k] = W[k][n]).  grid (16, 6): 4 k-tiles x 4 n-tiles of 64.
// ---------------------------------------------------------------------------
__global__ __launch_bounds__(256) void split_w(
    const float* __restrict__ W0, const float* __restrict__ W1, const float* __restrict__ W2,
    const float* __restrict__ W3, const float* __restrict__ W4, const float* __restrict__ W5,
    __half* __restrict__ wth, __half* __restrict__ wtl)
{
    __shared__ float T[64][65];
    const int which = blockIdx.y;
    const float* __restrict__ W = (which == 0) ? W0 : (which == 1) ? W1 : (which == 2) ? W2
                                 : (which == 3) ? W3 : (which == 4) ? W4 : W5;
    const int kx = (blockIdx.x & 3) * 64, nx = (blockIdx.x >> 2) * 64;
    const int t = threadIdx.x;
    #pragma unroll
    for (int p = 0; p < 4; ++p) {
        int id = p * 256 + t;
        int r = id >> 4, c4 = (id & 15) * 4;
        float4 v4 = *reinterpret_cast<const float4*>(W + (size_t)(kx + r) * 256 + nx + c4);
        T[r][c4 + 0] = v4.x; T[r][c4 + 1] = v4.y; T[r][c4 + 2] = v4.z; T[r][c4 + 3] = v4.w;
    }
    __syncthreads();
    const int n = t >> 2, kc = (t & 3) * 16;
    union { __half h[16]; uint4 u[2]; } hs, ls;
    #pragma unroll
    for (int i = 0; i < 16; ++i) {
        float v = T[kc + i][n];
        __half hv = __float2half(v);
        hs.h[i] = hv;
        ls.h[i] = __float2half(v - __half2float(hv));
    }
    size_t dst = ((size_t)(which * 256) + nx + n) * 256 + kx + kc;
    *reinterpret_cast<uint4*>(&wth[dst])     = hs.u[0];
    *reinterpret_cast<uint4*>(&wth[dst + 8]) = hs.u[1];
    *reinterpret_cast<uint4*>(&wtl[dst])     = ls.u[0];
    *reinterpret_cast<uint4*>(&wtl[dst + 8]) = ls.u[1];
}

// ---------------------------------------------------------------------------
// QKV GEMM on MFMA (split fp16, 3-term). X split [8192][256]; Wt split [6][n][k].
// Grid (128, 12): 64-row tile x (which,h). 4 waves: 2x2 of 32x32 tiles.
// Outputs: Q [bh][n][64] split (x0.125), K frag-linear split, V fp32 [bh][n][64].
// ---------------------------------------------------------------------------
__global__ __launch_bounds__(256) void qkv_gemm_mfma(
    const __half* __restrict__ xh, const __half* __restrict__ xl,
    const __half* __restrict__ wth, const __half* __restrict__ wtl, const int wbase,
    __half* __restrict__ Qhi, __half* __restrict__ Qlo,
    __half* __restrict__ Khi, __half* __restrict__ Klo,
    float* __restrict__ V)
{
    const int row0 = blockIdx.x * 64;
    const int nblk = blockIdx.y;
    const int which = nblk >> 2;             // 0=q,1=k,2=v
    const int h = nblk & 3;
    const int tid = threadIdx.x;
    const int wave = tid >> 6, lane = tid & 63;
    const int lq = lane & 31, hh = lane >> 5;
    const int wm = wave >> 1, wn = wave & 1;

    const size_t woff = ((size_t)((wbase + which) * 256) + h * 64 + wn * 32 + lq) * 256 + 8 * hh;
    const __half* __restrict__ wt_h = wth + woff;
    const __half* __restrict__ wt_l = wtl + woff;
    const size_t xoff = (size_t)(row0 + 32 * wm + lq) * 256 + 8 * hh;
    const __half* __restrict__ xr_h = xh + xoff;
    const __half* __restrict__ xr_l = xl + xoff;

    f32x16 st = zero16();
    #pragma unroll 4
    for (int ks = 0; ks < 16; ++ks) {
        half8 ah = *reinterpret_cast<const half8*>(xr_h + ks * 16);
        half8 al = *reinterpret_cast<const half8*>(xr_l + ks * 16);
        half8 bh = *reinterpret_cast<const half8*>(wt_h + ks * 16);
        half8 bl = *reinterpret_cast<const half8*>(wt_l + ks * 16);
        st = __builtin_amdgcn_mfma_f32_32x32x16_f16(ah, bh, st, 0, 0, 0);
        st = __builtin_amdgcn_mfma_f32_32x32x16_f16(al, bh, st, 0, 0, 0);
        st = __builtin_amdgcn_mfma_f32_32x32x16_f16(ah, bl, st, 0, 0, 0);
    }

    const int c = wn * 32 + lq;              // feature col 0..63
    if (which == 2) {
        #pragma unroll
        for (int r = 0; r < 16; ++r) {
            int row = row0 + 32 * wm + (r & 3) + 8 * (r >> 2) + 4 * hh;
            int b = row >> 11, n = row & 2047;
            V[((size_t)(b * 4 + h) * 2048 + n) * 64 + c] = st[r];
        }
    } else if (which == 0) {
        #pragma unroll
        for (int r = 0; r < 16; ++r) {
            int row = row0 + 32 * wm + (r & 3) + 8 * (r >> 2) + 4 * hh;
            int b = row >> 11, n = row & 2047;
            size_t idx = ((size_t)(b * 4 + h) * 2048 + n) * 64 + c;
            float v = st[r] * 0.125f;
            __half hv = __float2half(v);
            Qhi[idx] = hv;
            Qlo[idx] = __float2half(v - __half2float(hv));
        }
    } else {
        // K frag-linear: [bh][m/32][c/16][m%32][c%16]
        #pragma unroll
        for (int r = 0; r < 16; ++r) {
            int row = row0 + 32 * wm + (r & 3) + 8 * (r >> 2) + 4 * hh;
            int b = row >> 11, n = row & 2047;
            size_t idx = (((size_t)(b * 4 + h) * 64 + (n >> 5)) * 4 + (c >> 4)) * 512
                         + (size_t)(n & 31) * 16 + (c & 15);
            float v = st[r];
            __half hv = __float2half(v);
            Khi[idx] = hv;
            Klo[idx] = __float2half(v - __half2float(hv));
        }
    }
}

// ---------------------------------------------------------------------------
// V [bh][2048][64] fp32 -> frag-linear split fp16: [bh][m/16][c 0..63][m%16].
// ---------------------------------------------------------------------------
__global__ __launch_bounds__(256) void transpose_split_v(
    const float* __restrict__ V, __half* __restrict__ vthi, __half* __restrict__ vtlo)
{
    __shared__ float T[64][65];
    const int bh = blockIdx.y;
    const int m0 = blockIdx.x * 64;
    const float* __restrict__ Vb = V + (size_t)bh * 2048 * 64;
    const int t = threadIdx.x;
    #pragma unroll
    for (int p = 0; p < 4; ++p) {
        int id = p * 256 + t;
        int m = id >> 4;
        int c4 = (id & 15) * 4;
        float4 v4 = *reinterpret_cast<const float4*>(Vb + (size_t)(m0 + m) * 64 + c4);
        T[m][c4 + 0] = v4.x; T[m][c4 + 1] = v4.y; T[m][c4 + 2] = v4.z; T[m][c4 + 3] = v4.w;
    }
    __syncthreads();
    const int c = t >> 2, g = t & 3;         // g = 16-row subblock
    union { __half h[16]; uint4 u[2]; } hs, ls;
    #pragma unroll
    for (int i = 0; i < 16; ++i) {
        float v = T[g * 16 + i][c];
        __half hv = __float2half(v);
        hs.h[i] = hv;
        ls.h[i] = __float2half(v - __half2float(hv));
    }
    size_t dst = (((size_t)bh * 128) + (m0 >> 4) + g) * 1024 + (size_t)c * 16;
    *reinterpret_cast<uint4*>(&vthi[dst])     = hs.u[0];
    *reinterpret_cast<uint4*>(&vthi[dst + 8]) = hs.u[1];
    *reinterpret_cast<uint4*>(&vtlo[dst])     = ls.u[0];
    *reinterpret_cast<uint4*>(&vtlo[dst + 8]) = ls.u[1];
}

// ---------------------------------------------------------------------------
// Fused masked flash attention on MFMA (split fp16, swapped QK^T).
// Grid: 1024 blocks x 256 threads. Block = (bh, 32 q-rows); wave w = m-chunk.
// mode 0: write relu(out)+bias as split fp16 (hhi/hlo). mode 1: fp32 out.
// ---------------------------------------------------------------------------
__global__ __launch_bounds__(256) void gat_attn(
    const __half* __restrict__ qhi, const __half* __restrict__ qlo,
    const __half* __restrict__ khi, const __half* __restrict__ klo,
    const __half* __restrict__ vthi, const __half* __restrict__ vtlo,
    const unsigned long long* __restrict__ adjp,
    const float* __restrict__ bias, float* __restrict__ out,
    __half* __restrict__ hhi, __half* __restrict__ hlo, const int mode)
{
    const int lid = (blockIdx.x & 7) * 128 + (blockIdx.x >> 3);
    const int bh = lid >> 6, qt = lid & 63;
    const int b = bh >> 2, h = bh & 3;
    const int tid = threadIdx.x;
    const int wave = tid >> 6;
    const int lane = tid & 63;
    const int lq = lane & 31;
    const int hh = lane >> 5;
    const int q0 = qt * 32;

    const size_t qkbase = (size_t)bh * 2048 * 64;

    // Q fragments (B-operand: col = lane&31 = q, k = 16*ks + 8*hh + e)
    half8 qfh[4], qfl[4];
    {
        const __half* qr_h = qhi + qkbase + (size_t)(q0 + lq) * 64 + 8 * hh;
        const __half* qr_l = qlo + qkbase + (size_t)(q0 + lq) * 64 + 8 * hh;
        #pragma unroll
        for (int ks = 0; ks < 4; ++ks) {
            qfh[ks] = *reinterpret_cast<const half8*>(qr_h + ks * 16);
            qfl[ks] = *reinterpret_cast<const half8*>(qr_l + ks * 16);
        }
    }

    f32x16 o0 = zero16(), o1 = zero16();
    float mrun = -1e30f, lrun = 0.f;

    const unsigned long long* __restrict__ wrow = adjp + (size_t)(b * 2048 + q0 + lq) * 32;
    const int mbase = wave * 512;

    #pragma unroll 1
    for (int mw = 0; mw < 512; mw += 64) {
        const int mglob = mbase + mw;
        const unsigned long long wmask = wrow[mglob >> 6];

        #pragma unroll
        for (int hi2 = 0; hi2 < 2; ++hi2) {
            const int mt = mglob + hi2 * 32;

            // ---- scores S^T = K * Q^T (frag-linear K: coalesced 2KB loads) ----
            const __half* kb_h = khi + ((size_t)(bh * 64) + (mt >> 5)) * 2048 + lq * 16 + 8 * hh;
            const __half* kb_l = klo + ((size_t)(bh * 64) + (mt >> 5)) * 2048 + lq * 16 + 8 * hh;
            f32x16 st = zero16();
            __builtin_amdgcn_s_setprio(1);
            #pragma unroll
            for (int ks = 0; ks < 4; ++ks) {
                half8 kh = *reinterpret_cast<const half8*>(kb_h + ks * 512);
                half8 kl = *reinterpret_cast<const half8*>(kb_l + ks * 512);
                st = __builtin_amdgcn_mfma_f32_32x32x16_f16(kh, qfh[ks], st, 0, 0, 0);
                st = __builtin_amdgcn_mfma_f32_32x32x16_f16(kl, qfh[ks], st, 0, 0, 0);
                st = __builtin_amdgcn_mfma_f32_32x32x16_f16(kh, qfl[ks], st, 0, 0, 0);
            }
            __builtin_amdgcn_s_setprio(0);

            // ---- V loads issued early (hide L2 latency under softmax) ----
            const __half* vb_h = vthi + ((size_t)(bh * 128) + (mt >> 4)) * 1024 + lq * 16 + 8 * hh;
            const __half* vb_l = vtlo + ((size_t)(bh * 128) + (mt >> 4)) * 1024 + lq * 16 + 8 * hh;
            half8 va0h = *reinterpret_cast<const half8*>(vb_h);
            half8 vb0h = *reinterpret_cast<const half8*>(vb_h + 512);
            half8 va0l = *reinterpret_cast<const half8*>(vb_l);
            half8 vb0l = *reinterpret_cast<const half8*>(vb_l + 512);

            // ---- mask + online softmax ----
            const unsigned int v32 = (unsigned int)(wmask >> (hi2 * 32));
            const unsigned int w2 = v32 >> (4 * hh);
            const unsigned int bits = (w2 & 0xFu) | ((w2 >> 4) & 0xF0u)
                                    | ((w2 >> 8) & 0xF00u) | ((w2 >> 12) & 0xF000u);
            float tv[16];
            float pm = -1e30f;
            #pragma unroll
            for (int i = 0; i < 16; ++i) {
                tv[i] = ((bits >> i) & 1u) ? st[i] : -1e30f;
                pm = fmaxf(pm, tv[i]);
            }
            pm = fmaxf(pm, __shfl_xor(pm, 32, 64));
            if (!__all(pm <= mrun)) {
                float mnew = fmaxf(mrun, pm);
                float sf = __expf(mrun - mnew);   // 0 when mrun=-1e30, mnew finite
                mrun = mnew;
                lrun *= sf;
                o0 *= sf;
                o1 *= sf;
            }
            float e[16];
            #pragma unroll
            for (int i = 0; i < 16; ++i)
                e[i] = ((bits >> i) & 1u) ? __expf(tv[i] - mrun) : 0.f;
            float ps = (((e[0] + e[1]) + (e[2] + e[3])) + ((e[4] + e[5]) + (e[6] + e[7])))
                     + (((e[8] + e[9]) + (e[10] + e[11])) + ((e[12] + e[13]) + (e[14] + e[15])));
            ps += __shfl_xor(ps, 32, 64);
            lrun += ps;

            // ---- P -> split fp16 B-frags + PV (halved exchange: 2 shfl/group) ----
            half8 va1h, vb1h, va1l, vb1l;
            #pragma unroll
            for (int t2 = 0; t2 < 2; ++t2) {
                unsigned int Hp[4], Lp[4];
                #pragma unroll
                for (int p2 = 0; p2 < 4; ++p2) {
                    float ea = e[8 * t2 + 2 * p2], eb = e[8 * t2 + 2 * p2 + 1];
                    union { fp16x2 f; unsigned int u; } ch, cl;
                    ch.f = __builtin_amdgcn_cvt_pkrtz(ea, eb);
                    float fa = (float)ch.f[0], fb = (float)ch.f[1];
                    cl.f = __builtin_amdgcn_cvt_pkrtz(ea - fa, eb - fb);
                    Hp[p2] = ch.u; Lp[p2] = cl.u;
                }
                unsigned int hr1 = (unsigned)__shfl_xor((int)(hh ? Hp[0] : Hp[2]), 32, 64);
                unsigned int hr2 = (unsigned)__shfl_xor((int)(hh ? Hp[1] : Hp[3]), 32, 64);
                unsigned int lr1 = (unsigned)__shfl_xor((int)(hh ? Lp[0] : Lp[2]), 32, 64);
                unsigned int lr2 = (unsigned)__shfl_xor((int)(hh ? Lp[1] : Lp[3]), 32, 64);
                union { unsigned int u[4]; half8 hv; } Bh, Bl;
                Bh.u[0] = hh ? hr1 : Hp[0]; Bh.u[1] = hh ? hr2 : Hp[1];
                Bh.u[2] = hh ? Hp[2] : hr1; Bh.u[3] = hh ? Hp[3] : hr2;
                Bl.u[0] = hh ? lr1 : Lp[0]; Bl.u[1] = hh ? lr2 : Lp[1];
                Bl.u[2] = hh ? Lp[2] : lr1; Bl.u[3] = hh ? Lp[3] : lr2;

                if (t2 == 0) {   // issue t2=1 V loads before PV0
                    va1h = *reinterpret_cast<const half8*>(vb_h + 1024);
                    vb1h = *reinterpret_cast<const half8*>(vb_h + 1536);
                    va1l = *reinterpret_cast<const half8*>(vb_l + 1024);
                    vb1l = *reinterpret_cast<const half8*>(vb_l + 1536);
                }
                half8 vah = t2 ? va1h : va0h;
                half8 val = t2 ? va1l : va0l;
                half8 vbh2 = t2 ? vb1h : vb0h;
                half8 vbl2 = t2 ? vb1l : vb0l;

                __builtin_amdgcn_s_setprio(1);
                o0 = __builtin_amdgcn_mfma_f32_32x32x16_f16(vah, Bh.hv, o0, 0, 0, 0);
                o0 = __builtin_amdgcn_mfma_f32_32x32x16_f16(val, Bh.hv, o0, 0, 0, 0);
                o0 = __builtin_amdgcn_mfma_f32_32x32x16_f16(vah, Bl.hv, o0, 0, 0, 0);
                o1 = __builtin_amdgcn_mfma_f32_32x32x16_f16(vbh2, Bh.hv, o1, 0, 0, 0);
                o1 = __builtin_amdgcn_mfma_f32_32x32x16_f16(vbl2, Bh.hv, o1, 0, 0, 0);
                o1 = __builtin_amdgcn_mfma_f32_32x32x16_f16(vbh2, Bl.hv, o1, 0, 0, 0);
                __builtin_amdgcn_s_setprio(0);
            }
        }
    }

    // ---- in-LDS merge of the 4 m-chunk partials ----
    __shared__ float OS[4][64][33];
    __shared__ float MS[4][32];
    __shared__ float LS[4][32];

    #pragma unroll
    for (int ct = 0; ct < 2; ++ct) {
        #pragma unroll
        for (int i = 0; i < 16; ++i) {
            int c = 32 * ct + (i & 3) + 8 * (i >> 2) + 4 * hh;
            OS[wave][c][lq] = ct ? o1[i] : o0[i];
        }
    }
    if (hh == 0) { MS[wave][lq] = mrun; LS[wave][lq] = lrun; }
    __syncthreads();

    const int q = tid >> 3, c8 = (tid & 7) * 8;
    float m0v = MS[0][q], m1v = MS[1][q], m2v = MS[2][q], m3v = MS[3][q];
    float M = fmaxf(fmaxf(m0v, m1v), fmaxf(m2v, m3v));
    float w0 = __expf(m0v - M), w1 = __expf(m1v - M), w2w = __expf(m2v - M), w3 = __expf(m3v - M);
    float L = LS[0][q] * w0 + LS[1][q] * w1 + LS[2][q] * w2w + LS[3][q] * w3;
    float inv = 1.f / (L + 1e-16f);
    float res[8];
    #pragma unroll
    for (int j = 0; j < 8; ++j) {
        int c = c8 + j;
        float o = OS[0][c][q] * w0 + OS[1][c][q] * w1 + OS[2][c][q] * w2w + OS[3][c][q] * w3;
        res[j] = o * inv + bias[h * 64 + c];
    }
    size_t oidx = ((size_t)(b * 2048) + q0 + q) * 256 + h * 64 + c8;
    if (mode == 0) {
        union { __half h[8]; uint4 u; } sh, sl;
        #pragma unroll
        for (int j = 0; j < 8; ++j) {
            float val = fmaxf(res[j], 0.f);   // relu
            __half hv = __float2half(val);
            sh.h[j] = hv;
            sl.h[j] = __float2half(val - __half2float(hv));
        }
        *reinterpret_cast<uint4*>(&hhi[oidx]) = sh.u;
        *reinterpret_cast<uint4*>(&hlo[oidx]) = sl.u;
    } else {
        *reinterpret_cast<float4*>(&out[oidx])     = make_float4(res[0], res[1], res[2], res[3]);
        *reinterpret_cast<float4*>(&out[oidx + 4]) = make_float4(res[4], res[5], res[6], res[7]);
    }
}

// ---------------------------------------------------------------------------
extern "C" void kernel_launch(void* const* d_in, const int* in_sizes, int n_in,
                              void* d_out, int out_size, void* d_ws, size_t ws_size,
                              hipStream_t stream) {
    const float* x   = (const float*)d_in[0];
    const int*   adj = (const int*)d_in[1];
    const float* Wq1 = (const float*)d_in[2];
    const float* Wk1 = (const float*)d_in[3];
    const float* Wv1 = (const float*)d_in[4];
    const float* b1  = (const float*)d_in[5];
    const float* Wq2 = (const float*)d_in[6];
    const float* Wk2 = (const float*)d_in[7];
    const float* Wv2 = (const float*)d_in[8];
    const float* b2  = (const float*)d_in[9];
    float* outp = (float*)d_out;

    // workspace layout (MB offsets), total 44MB
    char* ws = (char*)d_ws;
    unsigned long long* adjp = (unsigned long long*)ws;        //  0..2
    __half* xhi = (__half*)(ws + ( 2u << 20));                 //  2..6   (reused as hhi)
    __half* xlo = (__half*)(ws + ( 6u << 20));                 //  6..10  (reused as hlo)
    __half* wth = (__half*)(ws + (10u << 20));                 // 10..11 (768KB)
    __half* wtl = (__half*)(ws + (11u << 20));                 // 11..12
    __half* qhi = (__half*)(ws + (12u << 20));
    __half* qlo = (__half*)(ws + (16u << 20));
    __half* khi = (__half*)(ws + (20u << 20));
    __half* klo = (__half*)(ws + (24u << 20));
    float*  v   = (float*) (ws + (28u << 20));                 // 28..36
    __half* vthi= (__half*)(ws + (36u << 20));
    __half* vtlo= (__half*)(ws + (40u << 20));

    pack_adj<<<65536, 256, 0, stream>>>(adj, adjp);
    split_x<<<2048, 256, 0, stream>>>(x, xhi, xlo);
    split_w<<<dim3(16, 6), 256, 0, stream>>>(Wq1, Wk1, Wv1, Wq2, Wk2, Wv2, wth, wtl);

    qkv_gemm_mfma<<<dim3(128, 12), 256, 0, stream>>>(xhi, xlo, wth, wtl, 0,
                                                     qhi, qlo, khi, klo, v);
    transpose_split_v<<<dim3(32, 16), 256, 0, stream>>>(v, vthi, vtlo);
    gat_attn<<<1024, 256, 0, stream>>>(qhi, qlo, khi, klo, vthi, vtlo, adjp, b1,
                                       outp, xhi, xlo, 0);

    qkv_gemm_mfma<<<dim3(128, 12), 256, 0, stream>>>(xhi, xlo, wth, wtl, 3,
                                                     qhi, qlo, khi, klo, v);
    transpose_split_v<<<dim3(32, 16), 256, 0, stream>>>(v, vthi, vtlo);
    gat_attn<<<1024, 256, 0, stream>>>(qhi, qlo, khi, klo, vthi, vtlo, adjp, b2,
                                       outp, xhi, xlo, 1);
}